// Round 4
// baseline (31521.094 us; speedup 1.0000x reference)
//
#include <hip/hip_runtime.h>

// EncoderDecoder LSTM: B=512, T=512, I=128, H=512.
// R4: persistent kernel, 32 batch-groups x 8 WGs (grid 256 = #CUs).
// All cross-WG data is WRITE-THROUGH (sc1 atomic stores) => release fences have
// no dirty L2 to flush (R3's buffer_wbl2 sweep was the 12us/step).
// Per-wave release-store flags + all-thread ballot polling; zero __syncthreads
// in the step loop. h loads are plain b128 after an acquire fence.
// Column interleave: n = q*256 + wv*64 + nt*16 + m, hcol = q*64+wv*16+(m&12)+nt,
// gate = m&3  => each lane's 4 h-values are contiguous (one u64 store).

typedef unsigned short u16;
typedef unsigned long long u64;
typedef __bf16 bf16x8 __attribute__((ext_vector_type(8)));
typedef float f32x4 __attribute__((ext_vector_type(4)));
typedef int i32x4 __attribute__((ext_vector_type(4)));

#define H_DIM 512
#define K_TOT 640
#define NSTEP 1024
#define NGRP  32
#define ROWS  16

__device__ __forceinline__ u16 f2bf(float f) {
  unsigned u = __builtin_bit_cast(unsigned, f);
  u += 0x7fffu + ((u >> 16) & 1u);   // RNE
  return (u16)(u >> 16);
}
__device__ __forceinline__ float sigm(float v) { return 1.0f / (1.0f + __expf(-v)); }
__device__ __forceinline__ float tanh_fast(float v) {
  float e = __expf(-2.0f * fabsf(v));
  float t = (1.0f - e) / (1.0f + e);
  return v < 0.0f ? -t : t;
}
__device__ __forceinline__ bf16x8 ld_frag(const u16* p) {
  i32x4 v = *reinterpret_cast<const i32x4*>(p);
  return __builtin_bit_cast(bf16x8, v);
}
__device__ __forceinline__ bf16x8 pack_x(const f32x4& x0, const f32x4& x1) {
  union { bf16x8 v; u16 u[8]; } r;
  r.u[0] = f2bf(x0[0]); r.u[1] = f2bf(x0[1]); r.u[2] = f2bf(x0[2]); r.u[3] = f2bf(x0[3]);
  r.u[4] = f2bf(x1[0]); r.u[5] = f2bf(x1[1]); r.u[6] = f2bf(x1[2]); r.u[7] = f2bf(x1[3]);
  return r.v;
}

// Wt[n][k] bf16: n in [0,2048). hcol(n) = (n>>8)*64 + ((n>>6)&3)*16 + (n&12) + ((n>>4)&3),
// gate(n) = n&3, j = gate*512 + hcol. k<512 -> Whh[j][k], else Wih[j][k-512].
__global__ void prep_w(const float* __restrict__ Whh, const float* __restrict__ Wih,
                       u16* __restrict__ Wt) {
  const int idx = blockIdx.x * 256 + threadIdx.x;
  const int n = idx / K_TOT;
  const int k = idx - n * K_TOT;
  const int hcol = (n >> 8) * 64 + ((n >> 6) & 3) * 16 + (n & 12) + ((n >> 4) & 3);
  const int j = (n & 3) * 512 + hcol;
  const float v = (k < H_DIM) ? Whh[(size_t)j * H_DIM + k]
                              : Wih[(size_t)j * 128 + (k - H_DIM)];
  Wt[idx] = f2bf(v);
}

__global__ void prep_bias(const float* __restrict__ bih, const float* __restrict__ bhh,
                          float* __restrict__ bias) {
  const int n = blockIdx.x * 256 + threadIdx.x;
  const int hcol = (n >> 8) * 64 + ((n >> 6) & 3) * 16 + (n & 12) + ((n >> 4) & 3);
  const int j = (n & 3) * 512 + hcol;
  bias[n] = bih[j] + bhh[j];
}

__global__ __launch_bounds__(256, 1)
void lstm_persist(const u16* __restrict__ encWt, const u16* __restrict__ decWt,
                  const float* __restrict__ encB, const float* __restrict__ decB,
                  const float* __restrict__ x, const float* __restrict__ fcW,
                  const float* __restrict__ fcb, u16* __restrict__ hbuf,
                  float* out, unsigned* flags)
{
  __shared__ u16 wxl[4][16][64 * 8];   // 64 KB: x-part weight frags, per-wave regions
  __shared__ float bias_l[256];

  const int tid  = threadIdx.x;
  const int lane = tid & 63;
  const int wv   = tid >> 6;
  const int g    = blockIdx.x & 31;    // batch group
  const int q    = blockIdx.x >> 5;    // WG-within-group 0..7
  const int row  = lane & 15;
  const int quad = lane >> 4;
  const int n0   = q * 256 + wv * 64;  // wave's gate-col base
  const int hcw  = q * 64 + wv * 16;   // wave's h-col base
  const int b0   = g * ROWS;
  unsigned* gflags = flags + g * 64;   // 32 used, padded to 256B/group

  bf16x8 Wf[16][4];                    // h-part weights: A-frags [kk][nt]
  auto stage = [&](const u16* Wt, const float* biasG) {
    __syncthreads();                   // wxl may still be in use by other waves
#pragma unroll
    for (int kk = 0; kk < 16; ++kk)
#pragma unroll
      for (int nt = 0; nt < 4; ++nt)
        Wf[kk][nt] = ld_frag(Wt + (size_t)(n0 + nt * 16 + row) * K_TOT + kk * 32 + quad * 8);
#pragma unroll
    for (int kk = 0; kk < 4; ++kk)
#pragma unroll
      for (int nt = 0; nt < 4; ++nt)
        *reinterpret_cast<i32x4*>(&wxl[wv][kk * 4 + nt][lane * 8]) =
            *reinterpret_cast<const i32x4*>(
                Wt + (size_t)(n0 + nt * 16 + row) * K_TOT + 512 + kk * 32 + quad * 8);
    bias_l[tid] = biasG[q * 256 + tid];
    __syncthreads();
  };
  stage(encWt, encB);

  float cc[4] = {0.f, 0.f, 0.f, 0.f};  // c cells: row=lane&15, hcol=hcw+quad*4+nt

  f32x4 xr[4][2];                      // x prefetch (fp32, packed at use)
  auto xpref = [&](int t) {
    const float* xp = x + ((size_t)(b0 + row) * 512 + t) * 128 + quad * 8;
#pragma unroll
    for (int kk = 0; kk < 4; ++kk) {
      xr[kk][0] = *reinterpret_cast<const f32x4*>(xp + kk * 32);
      xr[kk][1] = *reinterpret_cast<const f32x4*>(xp + kk * 32 + 4);
    }
  };
  xpref(0);

#pragma clang loop unroll(disable)
  for (int s = 0; s < NSTEP; ++s) {
    if (s == 512) stage(decWt, decB);  // enc -> dec (uniform, once)

    // ---- wait for h(s): all 32 producer-wave flags >= s (lane-parallel poll) ----
    if (s > 0) {
      const unsigned tgt = (unsigned)s;
      for (;;) {
        unsigned v = __hip_atomic_load(gflags + (lane & 31), __ATOMIC_RELAXED,
                                       __HIP_MEMORY_SCOPE_AGENT);
        if (__ballot(v >= tgt) == ~0ull) break;
        __builtin_amdgcn_s_sleep(1);
      }
      __builtin_amdgcn_fence(__ATOMIC_ACQUIRE, "agent");
    }

    // ---- h loads: plain b128 B-frags [n=row][k=quad*8+j] ----
    const u16* hs = hbuf + (size_t)((s & 1) * NGRP + g) * (ROWS * H_DIM);
    i32x4 hraw[16];
#pragma unroll
    for (int kk = 0; kk < 16; ++kk)
      hraw[kk] = *reinterpret_cast<const i32x4*>(hs + row * H_DIM + kk * 32 + quad * 8);

    // ---- gates GEMM: x-part first (hides h-load latency) ----
    bf16x8 xa[4];
#pragma unroll
    for (int kk = 0; kk < 4; ++kk) xa[kk] = pack_x(xr[kk][0], xr[kk][1]);
    f32x4 acc[4] = {};
#pragma unroll
    for (int kk = 0; kk < 4; ++kk)
#pragma unroll
      for (int nt = 0; nt < 4; ++nt) {
        bf16x8 wf = ld_frag(&wxl[wv][kk * 4 + nt][lane * 8]);
        acc[nt] = __builtin_amdgcn_mfma_f32_16x16x32_bf16(wf, xa[kk], acc[nt], 0, 0, 0);
      }
#pragma unroll
    for (int kk = 0; kk < 16; ++kk)
#pragma unroll
      for (int nt = 0; nt < 4; ++nt)
        acc[nt] = __builtin_amdgcn_mfma_f32_16x16x32_bf16(
            Wf[kk][nt], __builtin_bit_cast(bf16x8, hraw[kk]), acc[nt], 0, 0, 0);

    // ---- epilogue: acc[nt] = (i,f,g,o) for row=lane&15, hcol=hcw+quad*4+nt ----
    float hv[4];
#pragma unroll
    for (int nt = 0; nt < 4; ++nt) {
      f32x4 b4 = *reinterpret_cast<const f32x4*>(&bias_l[wv * 64 + nt * 16 + quad * 4]);
      const float iv = sigm(acc[nt][0] + b4[0]);
      const float fv = sigm(acc[nt][1] + b4[1]);
      const float gv = tanh_fast(acc[nt][2] + b4[2]);
      const float ov = sigm(acc[nt][3] + b4[3]);
      const float cn = fv * cc[nt] + iv * gv;
      cc[nt] = cn;
      hv[nt] = ov * tanh_fast(cn);
    }

    if (s < NSTEP - 1) {
      // write-through h (one u64/lane: 4 contiguous h cols), then release flag
      u16* hd = hbuf + (size_t)(((s + 1) & 1) * NGRP + g) * (ROWS * H_DIM);
      union { u64 v; u16 u[4]; } pk;
#pragma unroll
      for (int nt = 0; nt < 4; ++nt) pk.u[nt] = f2bf(hv[nt]);
      __hip_atomic_store(reinterpret_cast<u64*>(hd + row * H_DIM + hcw + quad * 4),
                         pk.v, __ATOMIC_RELAXED, __HIP_MEMORY_SCOPE_AGENT);
      if (lane == 0)
        __hip_atomic_store(gflags + q * 4 + wv, (unsigned)(s + 1),
                           __ATOMIC_RELEASE, __HIP_MEMORY_SCOPE_AGENT);
      xpref((s + 1) & 511);            // overlaps next poll
    } else {
      // fc on last decoder h: out[b] = sum_h h*fcW[h] + fcb
      float p = 0.f;
#pragma unroll
      for (int nt = 0; nt < 4; ++nt) p += hv[nt] * fcW[hcw + quad * 4 + nt];
      p += __shfl_xor(p, 16);
      p += __shfl_xor(p, 32);
      if (lane < 16) {
        if (q == 0 && wv == 0) p += fcb[0];
        atomicAdd(out + b0 + lane, p);
      }
    }
  }
}

extern "C" void kernel_launch(void* const* d_in, const int* in_sizes, int n_in,
                              void* d_out, int out_size, void* d_ws, size_t ws_size,
                              hipStream_t stream) {
  const float* x       = (const float*)d_in[0];
  const float* enc_Wih = (const float*)d_in[1];
  const float* enc_Whh = (const float*)d_in[2];
  const float* enc_bih = (const float*)d_in[3];
  const float* enc_bhh = (const float*)d_in[4];
  const float* dec_Wih = (const float*)d_in[5];
  const float* dec_Whh = (const float*)d_in[6];
  const float* dec_bih = (const float*)d_in[7];
  const float* dec_bhh = (const float*)d_in[8];
  const float* fc_W    = (const float*)d_in[9];
  const float* fc_b    = (const float*)d_in[10];
  float* out = (float*)d_out;

  // ws carve (~6.3 MB)
  char* ws = (char*)d_ws;
  u16*   encWt   = (u16*)ws;   ws += (size_t)2048 * K_TOT * 2;
  u16*   decWt   = (u16*)ws;   ws += (size_t)2048 * K_TOT * 2;
  float* encBias = (float*)ws; ws += 2048 * 4;
  float* decBias = (float*)ws; ws += 2048 * 4;
  u16*   hbuf    = (u16*)ws;   ws += (size_t)2 * NGRP * ROWS * H_DIM * 2;
  unsigned* flags = (unsigned*)ws; ws += NGRP * 64 * 4;   // 256B per group

  prep_w<<<(2048 * K_TOT) / 256, 256, 0, stream>>>(enc_Whh, enc_Wih, encWt);
  prep_w<<<(2048 * K_TOT) / 256, 256, 0, stream>>>(dec_Whh, dec_Wih, decWt);
  prep_bias<<<2048 / 256, 256, 0, stream>>>(enc_bih, enc_bhh, encBias);
  prep_bias<<<2048 / 256, 256, 0, stream>>>(dec_bih, dec_bhh, decBias);

  hipMemsetAsync(hbuf, 0, (size_t)NGRP * ROWS * H_DIM * 2, stream);  // h(0) = 0
  hipMemsetAsync(flags, 0, NGRP * 64 * 4, stream);
  hipMemsetAsync(out, 0, 512 * 4, stream);

  lstm_persist<<<256, 256, 0, stream>>>(encWt, decWt, encBias, decBias, x,
                                        fc_W, fc_b, hbuf, out, flags);
}

// Round 7
// 7938.673 us; speedup vs baseline: 3.9706x; 3.9706x over previous
//
#include <hip/hip_runtime.h>

// EncoderDecoder LSTM: B=512, T=512, I=128, H=512.
// R7: persistent kernel, 32 batch-groups x 8 WGs (grid 256 = #CUs).
// Coherence law learned R3-R6: vmcnt-ack of write-through stores / NON-returning
// atomics does NOT mean MALL-commit (flag can pass h in flight). RETURNING
// atomics must execute at the MALL to produce data => vmcnt(0) on the return is
// a true commit fence. h published via returning atomicExch (returns kept live),
// then vmcnt(0), then relaxed flag store. Consumer: ballot-poll relaxed-agent
// flag loads + relaxed-agent u64 h loads (bypass stale L2 -- R3-proven), staged
// once per WG through LDS. Zero wbl2/inv in the loop.

typedef unsigned short u16;
typedef unsigned long long u64;
typedef __bf16 bf16x8 __attribute__((ext_vector_type(8)));
typedef float f32x4 __attribute__((ext_vector_type(4)));
typedef int i32x4 __attribute__((ext_vector_type(4)));

#define H_DIM 512
#define K_TOT 640
#define NSTEP 1024
#define NGRP  32
#define ROWS  16
#define HLDS  520   // LDS h row stride in u16 (pad: frag ds_read_b128 2-way)

__device__ __forceinline__ u16 f2bf(float f) {
  unsigned u = __builtin_bit_cast(unsigned, f);
  u += 0x7fffu + ((u >> 16) & 1u);   // RNE
  return (u16)(u >> 16);
}
__device__ __forceinline__ float sigm(float v) { return 1.0f / (1.0f + __expf(-v)); }
__device__ __forceinline__ float tanh_fast(float v) {
  float e = __expf(-2.0f * fabsf(v));
  float t = (1.0f - e) / (1.0f + e);
  return v < 0.0f ? -t : t;
}
__device__ __forceinline__ bf16x8 ld_frag(const u16* p) {
  i32x4 v = *reinterpret_cast<const i32x4*>(p);
  return __builtin_bit_cast(bf16x8, v);
}
__device__ __forceinline__ bf16x8 pack_x(const f32x4& x0, const f32x4& x1) {
  union { bf16x8 v; u16 u[8]; } r;
  r.u[0] = f2bf(x0[0]); r.u[1] = f2bf(x0[1]); r.u[2] = f2bf(x0[2]); r.u[3] = f2bf(x0[3]);
  r.u[4] = f2bf(x1[0]); r.u[5] = f2bf(x1[1]); r.u[6] = f2bf(x1[2]); r.u[7] = f2bf(x1[3]);
  return r.v;
}

// Wt[n][k] bf16: n in [0,2048). hcol(n) = (n>>8)*64 + ((n>>6)&3)*16 + (n&12) + ((n>>4)&3),
// gate(n) = n&3, j = gate*512 + hcol. k<512 -> Whh[j][k], else Wih[j][k-512].
__global__ void prep_w(const float* __restrict__ Whh, const float* __restrict__ Wih,
                       u16* __restrict__ Wt) {
  const int idx = blockIdx.x * 256 + threadIdx.x;
  const int n = idx / K_TOT;
  const int k = idx - n * K_TOT;
  const int hcol = (n >> 8) * 64 + ((n >> 6) & 3) * 16 + (n & 12) + ((n >> 4) & 3);
  const int j = (n & 3) * 512 + hcol;
  const float v = (k < H_DIM) ? Whh[(size_t)j * H_DIM + k]
                              : Wih[(size_t)j * 128 + (k - H_DIM)];
  Wt[idx] = f2bf(v);
}

__global__ void prep_bias(const float* __restrict__ bih, const float* __restrict__ bhh,
                          float* __restrict__ bias) {
  const int n = blockIdx.x * 256 + threadIdx.x;
  const int hcol = (n >> 8) * 64 + ((n >> 6) & 3) * 16 + (n & 12) + ((n >> 4) & 3);
  const int j = (n & 3) * 512 + hcol;
  bias[n] = bih[j] + bhh[j];
}

__global__ __launch_bounds__(256, 1)
void lstm_persist(const u16* __restrict__ encWt, const u16* __restrict__ decWt,
                  const float* __restrict__ encB, const float* __restrict__ decB,
                  const float* __restrict__ x, const float* __restrict__ fcW,
                  const float* __restrict__ fcb, u16* __restrict__ hbuf,
                  float* out, unsigned* flags)
{
  __shared__ u16 wxl[4][16][64 * 8];     // 64 KB: x-part weight frags, per-wave
  __shared__ u16 hsh[ROWS * HLDS + 8];   // 16.6 KB: staged h [row][col], stride 520
  __shared__ float bias_l[256];

  const int tid  = threadIdx.x;
  const int lane = tid & 63;
  const int wv   = tid >> 6;
  const int g    = blockIdx.x & 31;      // batch group
  const int q    = blockIdx.x >> 5;      // WG-within-group 0..7
  const int row  = lane & 15;
  const int quad = lane >> 4;
  const int n0   = q * 256 + wv * 64;    // wave's gate-col base
  const int hcw  = q * 64 + wv * 16;     // wave's h-col base
  const int b0   = g * ROWS;
  unsigned* gflags = flags + g * 64;     // 32 used, 256B/group padding

  // staging map: thread covers row sr, 16B chunks ch = sc16 + 16j (j=0..3)
  const int sr   = tid >> 4;             // 0..15
  const int sc16 = tid & 15;             // 0..15

  bf16x8 Wf[16][4];                      // h-part weights: A-frags [kk][nt]
  auto stage = [&](const u16* Wt, const float* biasG) {
    __syncthreads();                     // wxl may still be in use
#pragma unroll
    for (int kk = 0; kk < 16; ++kk)
#pragma unroll
      for (int nt = 0; nt < 4; ++nt)
        Wf[kk][nt] = ld_frag(Wt + (size_t)(n0 + nt * 16 + row) * K_TOT + kk * 32 + quad * 8);
#pragma unroll
    for (int kk = 0; kk < 4; ++kk)
#pragma unroll
      for (int nt = 0; nt < 4; ++nt)
        *reinterpret_cast<i32x4*>(&wxl[wv][kk * 4 + nt][lane * 8]) =
            *reinterpret_cast<const i32x4*>(
                Wt + (size_t)(n0 + nt * 16 + row) * K_TOT + 512 + kk * 32 + quad * 8);
    bias_l[tid] = biasG[q * 256 + tid];
    __syncthreads();
  };
  stage(encWt, encB);

  float cc[4] = {0.f, 0.f, 0.f, 0.f};    // c cells: row=lane&15, hcol=hcw+quad*4+nt
  u64 junk = 0;                          // keeps atomicExch returns live

  f32x4 xr[4][2];                        // x prefetch (fp32, packed at use)
  auto xpref = [&](int t) {
    const float* xp = x + ((size_t)(b0 + row) * 512 + t) * 128 + quad * 8;
#pragma unroll
    for (int kk = 0; kk < 4; ++kk) {
      xr[kk][0] = *reinterpret_cast<const f32x4*>(xp + kk * 32);
      xr[kk][1] = *reinterpret_cast<const f32x4*>(xp + kk * 32 + 4);
    }
  };
  xpref(0);

  u64* lds64 = reinterpret_cast<u64*>(hsh);

#pragma clang loop unroll(disable)
  for (int s = 0; s < NSTEP; ++s) {
    if (s == 512) stage(decWt, decB);    // enc -> dec (uniform, once)

    // ---- wait for h(s): all 32 producer-wave flags >= s ----
    if (s > 0) {
      const unsigned tgt = (unsigned)s;
      for (;;) {
        unsigned v = __hip_atomic_load(gflags + (lane & 31), __ATOMIC_RELAXED,
                                       __HIP_MEMORY_SCOPE_AGENT);
        if (__ballot(v >= tgt) == ~0ull) break;
        __builtin_amdgcn_s_sleep(1);
      }
      asm volatile("" ::: "memory");     // compiler barrier only (h read via MALL)
    }

    // ---- stage h(s) into LDS: 8 relaxed-agent u64 loads (coalesced) per thread ----
    {
      const u64* hp = (const u64*)(hbuf + (size_t)((s & 1) * NGRP + g) * (ROWS * H_DIM));
      u64 tmp[8];
#pragma unroll
      for (int j = 0; j < 4; ++j) {
        const int ch = sc16 + 16 * j;
        tmp[2 * j]     = __hip_atomic_load(hp + sr * 128 + ch * 2,     __ATOMIC_RELAXED,
                                           __HIP_MEMORY_SCOPE_AGENT);
        tmp[2 * j + 1] = __hip_atomic_load(hp + sr * 128 + ch * 2 + 1, __ATOMIC_RELAXED,
                                           __HIP_MEMORY_SCOPE_AGENT);
      }
#pragma unroll
      for (int j = 0; j < 4; ++j) {
        const int ch = sc16 + 16 * j;
        lds64[sr * 130 + ch * 2]     = tmp[2 * j];
        lds64[sr * 130 + ch * 2 + 1] = tmp[2 * j + 1];
      }
    }

    // ---- x-part MFMAs (independent of h) while h staging drains ----
    bf16x8 xa[4];
#pragma unroll
    for (int kk = 0; kk < 4; ++kk) xa[kk] = pack_x(xr[kk][0], xr[kk][1]);
    f32x4 acc[4] = {};
#pragma unroll
    for (int kk = 0; kk < 4; ++kk)
#pragma unroll
      for (int nt = 0; nt < 4; ++nt) {
        bf16x8 wf = ld_frag(&wxl[wv][kk * 4 + nt][lane * 8]);
        acc[nt] = __builtin_amdgcn_mfma_f32_16x16x32_bf16(wf, xa[kk], acc[nt], 0, 0, 0);
      }
    __syncthreads();                     // h fully staged

    // ---- h-part MFMAs: B-frags from LDS ----
#pragma unroll
    for (int kk = 0; kk < 16; ++kk) {
      bf16x8 hf = ld_frag(&hsh[row * HLDS + kk * 32 + quad * 8]);
#pragma unroll
      for (int nt = 0; nt < 4; ++nt)
        acc[nt] = __builtin_amdgcn_mfma_f32_16x16x32_bf16(Wf[kk][nt], hf, acc[nt], 0, 0, 0);
    }

    // ---- epilogue: acc[nt] = (i,f,g,o) for row=lane&15, hcol=hcw+quad*4+nt ----
    float hv[4];
#pragma unroll
    for (int nt = 0; nt < 4; ++nt) {
      f32x4 b4 = *reinterpret_cast<const f32x4*>(&bias_l[wv * 64 + nt * 16 + quad * 4]);
      const float iv = sigm(acc[nt][0] + b4[0]);
      const float fv = sigm(acc[nt][1] + b4[1]);
      const float gv = tanh_fast(acc[nt][2] + b4[2]);
      const float ov = sigm(acc[nt][3] + b4[3]);
      const float cn = fv * cc[nt] + iv * gv;
      cc[nt] = cn;
      hv[nt] = ov * tanh_fast(cn);
    }

    if (s < NSTEP - 1) {
      // publish h via RETURNING atomic swap: the return value can only be
      // produced by execution at the MALL, so vmcnt(0) on it == commit fence.
      u16* hd = hbuf + (size_t)(((s + 1) & 1) * NGRP + g) * (ROWS * H_DIM);
      union { u64 v; u16 u[4]; } pk;
#pragma unroll
      for (int nt = 0; nt < 4; ++nt) pk.u[nt] = f2bf(hv[nt]);
      u64 old = __hip_atomic_exchange(
          reinterpret_cast<u64*>(hd + row * H_DIM + hcw + quad * 4), pk.v,
          __ATOMIC_RELAXED, __HIP_MEMORY_SCOPE_AGENT);
      junk ^= old;                       // keep return live (see end-of-kernel sink)
      xpref((s + 1) & 511);              // plain loads, overlap the swap round-trip
      asm volatile("s_waitcnt vmcnt(0)" ::: "memory");   // h committed at MALL
      if (lane == 0)
        __hip_atomic_store(gflags + q * 4 + wv, (unsigned)(s + 1),
                           __ATOMIC_RELAXED, __HIP_MEMORY_SCOPE_AGENT);
    } else {
      // fc on last decoder h: out[b] = sum_h h*fcW[h] + fcb
      float p = 0.f;
#pragma unroll
      for (int nt = 0; nt < 4; ++nt) p += hv[nt] * fcW[hcw + quad * 4 + nt];
      p += __shfl_xor(p, 16);
      p += __shfl_xor(p, 32);
      if (lane < 16) {
        if (q == 0 && wv == 0) p += fcb[0];
        atomicAdd(out + b0 + lane, p);
      }
    }
  }

  // Sink for the swap returns: wave-reduce and store into flag padding (unused).
  junk ^= __shfl_xor(junk, 1);  junk ^= __shfl_xor(junk, 2);
  junk ^= __shfl_xor(junk, 4);  junk ^= __shfl_xor(junk, 8);
  junk ^= __shfl_xor(junk, 16); junk ^= __shfl_xor(junk, 32);
  if (lane == 0)
    gflags[32 + q * 4 + wv] = (unsigned)(junk ^ (junk >> 32));
}

extern "C" void kernel_launch(void* const* d_in, const int* in_sizes, int n_in,
                              void* d_out, int out_size, void* d_ws, size_t ws_size,
                              hipStream_t stream) {
  const float* x       = (const float*)d_in[0];
  const float* enc_Wih = (const float*)d_in[1];
  const float* enc_Whh = (const float*)d_in[2];
  const float* enc_bih = (const float*)d_in[3];
  const float* enc_bhh = (const float*)d_in[4];
  const float* dec_Wih = (const float*)d_in[5];
  const float* dec_Whh = (const float*)d_in[6];
  const float* dec_bih = (const float*)d_in[7];
  const float* dec_bhh = (const float*)d_in[8];
  const float* fc_W    = (const float*)d_in[9];
  const float* fc_b    = (const float*)d_in[10];
  float* out = (float*)d_out;

  // ws carve (~6.3 MB)
  char* ws = (char*)d_ws;
  u16*   encWt   = (u16*)ws;   ws += (size_t)2048 * K_TOT * 2;
  u16*   decWt   = (u16*)ws;   ws += (size_t)2048 * K_TOT * 2;
  float* encBias = (float*)ws; ws += 2048 * 4;
  float* decBias = (float*)ws; ws += 2048 * 4;
  u16*   hbuf    = (u16*)ws;   ws += (size_t)2 * NGRP * ROWS * H_DIM * 2;
  unsigned* flags = (unsigned*)ws; ws += NGRP * 64 * 4;   // 256B per group

  prep_w<<<(2048 * K_TOT) / 256, 256, 0, stream>>>(enc_Whh, enc_Wih, encWt);
  prep_w<<<(2048 * K_TOT) / 256, 256, 0, stream>>>(dec_Whh, dec_Wih, decWt);
  prep_bias<<<2048 / 256, 256, 0, stream>>>(enc_bih, enc_bhh, encBias);
  prep_bias<<<2048 / 256, 256, 0, stream>>>(dec_bih, dec_bhh, decBias);

  hipMemsetAsync(hbuf, 0, (size_t)NGRP * ROWS * H_DIM * 2, stream);  // h(0) = 0
  hipMemsetAsync(flags, 0, NGRP * 64 * 4, stream);
  hipMemsetAsync(out, 0, 512 * 4, stream);

  lstm_persist<<<256, 256, 0, stream>>>(encWt, decWt, encBias, decBias, x,
                                        fc_W, fc_b, hbuf, out, flags);
}